// Round 1
// baseline (342.558 us; speedup 1.0000x reference)
//
#include <hip/hip_runtime.h>
#include <math.h>

#define BSZ 16
#define NQ 300
#define NT 50
#define K3 51
#define NPRED (BSZ*NQ)     // 4800
#define NTGT  (BSZ*NT)     // 800
#define NC    (NPRED*NTGT) // 3,840,000

// ws layout (float offsets)
#define WS_DISTKP 0            // 800*51 = 40800
#define WS_TLT    40800        // 800*3
#define WS_TRB    43200        // 800*3
#define WS_TVOL   45600        // 800
#define WS_PLT    46400        // 4800*3
#define WS_PRB    60800        // 4800*3
#define WS_PVOL   75200        // 4800
#define WS_COSTT  80000        // 16*50*300 = 240000  (costT[b][t][q], row-major 50x300)
// total 320000 floats = 1.28 MB

__global__ void prep_kernel(const float* __restrict__ pred_boxes,
                            const float* __restrict__ tgt_boxes,
                            const float* __restrict__ tgt_kp,
                            float* __restrict__ ws)
{
    int tid = blockIdx.x * blockDim.x + threadIdx.x;
    float* dist_kp = ws + WS_DISTKP;
    float* tlt  = ws + WS_TLT;
    float* trb  = ws + WS_TRB;
    float* tvol = ws + WS_TVOL;
    float* plt  = ws + WS_PLT;
    float* prb  = ws + WS_PRB;
    float* pvol = ws + WS_PVOL;

    if (tid < NPRED) {
        float c0 = pred_boxes[tid*6+0], c1 = pred_boxes[tid*6+1], c2 = pred_boxes[tid*6+2];
        float s0 = pred_boxes[tid*6+3], s1 = pred_boxes[tid*6+4], s2 = pred_boxes[tid*6+5];
        float l0 = c0 - 0.5f*s0, l1 = c1 - 0.5f*s1, l2 = c2 - 0.5f*s2;
        float r0 = c0 + 0.5f*s0, r1 = c1 + 0.5f*s1, r2 = c2 + 0.5f*s2;
        plt[tid*3+0]=l0; plt[tid*3+1]=l1; plt[tid*3+2]=l2;
        prb[tid*3+0]=r0; prb[tid*3+1]=r1; prb[tid*3+2]=r2;
        pvol[tid] = (r0-l0)*(r1-l1)*(r2-l2);
    }
    if (tid < NTGT) {
        float c0 = tgt_boxes[tid*6+0], c1 = tgt_boxes[tid*6+1], c2 = tgt_boxes[tid*6+2];
        float s0 = tgt_boxes[tid*6+3], s1 = tgt_boxes[tid*6+4], s2 = tgt_boxes[tid*6+5];
        float l0 = c0 - 0.5f*s0, l1 = c1 - 0.5f*s1, l2 = c2 - 0.5f*s2;
        float r0 = c0 + 0.5f*s0, r1 = c1 + 0.5f*s1, r2 = c2 + 0.5f*s2;
        tlt[tid*3+0]=l0; tlt[tid*3+1]=l1; tlt[tid*3+2]=l2;
        trb[tid*3+0]=r0; trb[tid*3+1]=r1; trb[tid*3+2]=r2;
        tvol[tid] = (r0-l0)*(r1-l1)*(r2-l2);
        float L[3] = {l0, l1, l2};
        float S[3] = {s0, s1, s2};
        #pragma unroll
        for (int c = 0; c < K3; ++c) {
            int d = c % 3;
            dist_kp[tid*K3 + c] = (tgt_kp[tid*K3 + c] - L[d]) / S[d];
        }
    }
}

#define PT 32
#define TT 80

__global__ __launch_bounds__(256) void cost_kernel(const float* __restrict__ pred_kp,
                                                   float* __restrict__ ws,
                                                   float* __restrict__ C)
{
    const float* dist_kp = ws + WS_DISTKP;
    const float* tlt  = ws + WS_TLT;
    const float* trb  = ws + WS_TRB;
    const float* tvol = ws + WS_TVOL;
    const float* plt  = ws + WS_PLT;
    const float* prb  = ws + WS_PRB;
    const float* pvol = ws + WS_PVOL;
    float* costT = ws + WS_COSTT;

    __shared__ float s_pk[PT*K3];
    __shared__ float s_dk[TT*K3];
    __shared__ float s_plt[PT*3], s_prb[PT*3], s_pv[PT];
    __shared__ float s_tlt[TT*3], s_trb[TT*3], s_tv[TT];

    int p0 = blockIdx.x * PT;
    int t0 = blockIdx.y * TT;
    int tid = threadIdx.x;

    for (int i = tid; i < PT*K3; i += 256) s_pk[i] = pred_kp[p0*K3 + i];
    for (int i = tid; i < TT*K3; i += 256) s_dk[i] = dist_kp[t0*K3 + i];
    for (int i = tid; i < PT*3; i += 256) { s_plt[i] = plt[p0*3 + i]; s_prb[i] = prb[p0*3 + i]; }
    for (int i = tid; i < TT*3; i += 256) { s_tlt[i] = tlt[t0*3 + i]; s_trb[i] = trb[t0*3 + i]; }
    if (tid < PT) s_pv[tid] = pvol[p0 + tid];
    if (tid < TT) s_tv[tid] = tvol[t0 + tid];
    __syncthreads();

    #pragma unroll
    for (int r = 0; r < 10; ++r) {
        int e  = tid + 256*r;          // 0..2559
        int pl = e / TT;               // 0..31
        int tl = e - pl*TT;            // 0..79
        const float* a  = s_pk + pl*K3;
        const float* bb = s_dk + tl*K3;
        float sum = 0.f;
        #pragma unroll
        for (int c = 0; c < K3; ++c) sum += fabsf(a[c] - bb[c]);

        float inter = 1.f, evol = 1.f;
        #pragma unroll
        for (int d = 0; d < 3; ++d) {
            float pl_d = s_plt[pl*3+d], tl_d = s_tlt[tl*3+d];
            float pr_d = s_prb[pl*3+d], tr_d = s_trb[tl*3+d];
            float lo = fmaxf(pl_d, tl_d);
            float hi = fminf(pr_d, tr_d);
            inter *= fmaxf(hi - lo, 0.f);
            float el = fminf(pl_d, tl_d);
            float er = fmaxf(pr_d, tr_d);
            evol *= fmaxf(er - el, 0.f);
        }
        float uni  = s_pv[pl] + s_tv[tl] - inter;
        float giou = inter/uni - (evol - uni)/evol;
        float val  = sum - giou;       // COST_KEYPOINT*kp + COST_GIOU*(-giou)

        int p = p0 + pl, t = t0 + tl;
        C[p*NTGT + t] = val;
        int b = p / NQ;
        int trel = t - b*NT;
        if (trel >= 0 && trel < NT) {
            costT[b*(NT*NQ) + trel*NQ + (p - b*NQ)] = val;
        }
    }
}

// One wave per batch. Exact port of the reference shortest-augmenting-path LAP
// on the transposed cost (n=50 rows, m=300 cols), float64 duals.
__global__ __launch_bounds__(64) void lap_kernel(const float* __restrict__ costT,
                                                 float* __restrict__ out_idx)
{
    int b  = blockIdx.x;
    int ln = threadIdx.x;
    const float* cst = costT + b*(NT*NQ);   // [50][300]

    __shared__ double u[NT];
    __shared__ double v[NQ];
    __shared__ double shortest[NQ];
    __shared__ int path[NQ];
    __shared__ int row4col[NQ];
    __shared__ int col4row[NT];
    __shared__ unsigned char SC[NQ];
    __shared__ unsigned char SR[NT];

    for (int j = ln; j < NQ; j += 64) { v[j] = 0.0; row4col[j] = -1; }
    if (ln < NT) { u[ln] = 0.0; col4row[ln] = -1; }
    __syncthreads();

    for (int curRow = 0; curRow < NT; ++curRow) {
        for (int j = ln; j < NQ; j += 64) {
            shortest[j] = __builtin_inf();
            path[j] = -1;
            SC[j] = 0;
        }
        if (ln < NT) SR[ln] = 0;
        __syncthreads();

        int i = curRow;
        double minVal = 0.0;
        int sink = -1;
        while (sink < 0) {
            if (ln == 0) SR[i] = 1;
            double ui = u[i];
            double best = __builtin_inf();
            int bestj = 1 << 30;
            for (int j = ln; j < NQ; j += 64) {
                if (!SC[j]) {
                    double r = ((minVal + (double)cst[i*NQ + j]) - ui) - v[j];
                    if (r < shortest[j]) { shortest[j] = r; path[j] = i; }
                    double s = shortest[j];
                    if (s < best || (s == best && j < bestj)) { best = s; bestj = j; }
                }
            }
            // wave argmin, ties -> lowest column index (matches np.argmin)
            #pragma unroll
            for (int off = 32; off > 0; off >>= 1) {
                double ov = __shfl_xor(best, off);
                int    oj = __shfl_xor(bestj, off);
                if (ov < best || (ov == best && oj < bestj)) { best = ov; bestj = oj; }
            }
            minVal = best;
            int jstar = bestj;
            __syncthreads();                 // shortest/path writes done before next scan
            if (ln == 0) SC[jstar] = 1;
            int rc = row4col[jstar];
            if (rc < 0) sink = jstar; else i = rc;
            __syncthreads();                 // SC[jstar] visible for next scan
        }

        // dual updates (before augmentation, reading pre-augment col4row)
        if (ln < NT) {
            if (ln == curRow)      u[ln] += minVal;
            else if (SR[ln])       u[ln] += minVal - shortest[col4row[ln]];
        }
        for (int j = ln; j < NQ; j += 64)
            if (SC[j]) v[j] -= minVal - shortest[j];
        __syncthreads();

        // augment (serial, lane 0)
        if (ln == 0) {
            int j = sink;
            while (1) {
                int i2 = path[j];
                row4col[j] = i2;
                int tmp = col4row[i2];
                col4row[i2] = j;
                j = tmp;
                if (i2 == curRow) break;
            }
        }
        __syncthreads();
    }

    // indices: row0 = sorted pred indices, row1 = matched tgt indices
    if (ln < NT) {
        int myc = col4row[ln];
        int rank = 0;
        for (int s = 0; s < NT; ++s) rank += (col4row[s] < myc) ? 1 : 0;
        out_idx[b*(2*NT) + rank]      = (float)myc;
        out_idx[b*(2*NT) + NT + rank] = (float)ln;
    }
}

extern "C" void kernel_launch(void* const* d_in, const int* in_sizes, int n_in,
                              void* d_out, int out_size, void* d_ws, size_t ws_size,
                              hipStream_t stream)
{
    const float* pred_kp    = (const float*)d_in[0];
    const float* pred_boxes = (const float*)d_in[1];
    const float* tgt_boxes  = (const float*)d_in[2];
    const float* tgt_kp     = (const float*)d_in[3];
    float* ws  = (float*)d_ws;
    float* C   = (float*)d_out;
    float* idx = C + NC;

    prep_kernel<<<(NPRED + 255)/256, 256, 0, stream>>>(pred_boxes, tgt_boxes, tgt_kp, ws);
    dim3 grid(NPRED/PT, NTGT/TT);   // 150 x 10
    cost_kernel<<<grid, 256, 0, stream>>>(pred_kp, ws, C);
    lap_kernel<<<BSZ, 64, 0, stream>>>(ws + WS_COSTT, idx);
}

// Round 2
// 150.376 us; speedup vs baseline: 2.2780x; 2.2780x over previous
//
#include <hip/hip_runtime.h>
#include <math.h>

#define BSZ 16
#define NQ 300
#define NT 50
#define K3 51
#define NPRED (BSZ*NQ)     // 4800
#define NTGT  (BSZ*NT)     // 800
#define NC    (NPRED*NTGT) // 3,840,000
#define TSTRIDE 301        // lap tile row stride (floats), odd -> conflict-free writes
#define SMEMF 15104        // floats: 50*301 tile + slack (60.4 KB)

// ---------------- DPP wave-min helpers (wave64, all lanes active) ----------------
// ctrl: 0xB1 quad_perm[1,0,3,2] (xor1), 0x4E quad_perm[2,3,0,1] (xor2),
// 0x141 row_half_mirror, 0x140 row_mirror, 0x142 row_bcast15, 0x143 row_bcast31
template<int CTRL, int RMASK>
__device__ __forceinline__ double dpp_minstep_f64(double x) {
    long long bb = __double_as_longlong(x);
    int lo = (int)(bb & 0xFFFFFFFFll);
    int hi = (int)(bb >> 32);
    int mlo = __builtin_amdgcn_update_dpp(lo, lo, CTRL, RMASK, 0xF, false);
    int mhi = __builtin_amdgcn_update_dpp(hi, hi, CTRL, RMASK, 0xF, false);
    double other = __longlong_as_double(((long long)mhi << 32) | (long long)(unsigned)mlo);
    return fmin(x, other);
}
template<int CTRL, int RMASK>
__device__ __forceinline__ unsigned dpp_minstep_u32(unsigned x) {
    int m = __builtin_amdgcn_update_dpp((int)x, (int)x, CTRL, RMASK, 0xF, false);
    unsigned um = (unsigned)m;
    return um < x ? um : x;
}
__device__ __forceinline__ double wave_min_f64(double x) {
    x = dpp_minstep_f64<0xB1, 0xF>(x);
    x = dpp_minstep_f64<0x4E, 0xF>(x);
    x = dpp_minstep_f64<0x141, 0xF>(x);
    x = dpp_minstep_f64<0x140, 0xF>(x);
    x = dpp_minstep_f64<0x142, 0xA>(x);   // lanes 16-31,48-63 <- lane 15/47
    x = dpp_minstep_f64<0x143, 0xC>(x);   // lanes 32-63 <- lane 31; lane 63 = global min
    long long bb = __double_as_longlong(x);
    int lo = __builtin_amdgcn_readlane((int)(bb & 0xFFFFFFFFll), 63);
    int hi = __builtin_amdgcn_readlane((int)(bb >> 32), 63);
    return __longlong_as_double(((long long)hi << 32) | (long long)(unsigned)lo);
}
__device__ __forceinline__ unsigned wave_min_u32(unsigned x) {
    x = dpp_minstep_u32<0xB1, 0xF>(x);
    x = dpp_minstep_u32<0x4E, 0xF>(x);
    x = dpp_minstep_u32<0x141, 0xF>(x);
    x = dpp_minstep_u32<0x140, 0xF>(x);
    x = dpp_minstep_u32<0x142, 0xA>(x);
    x = dpp_minstep_u32<0x143, 0xC>(x);
    return (unsigned)__builtin_amdgcn_readlane((int)x, 63);
}

// Identical formula/op-order used by BOTH paths -> bitwise-identical cost values.
__device__ __forceinline__ float giou_cost(
    float plt0, float plt1, float plt2, float prb0, float prb1, float prb2, float pvol,
    float tlt0, float tlt1, float tlt2, float trb0, float trb1, float trb2, float tvol)
{
    float inter = fmaxf(fminf(prb0,trb0) - fmaxf(plt0,tlt0), 0.f);
    inter *= fmaxf(fminf(prb1,trb1) - fmaxf(plt1,tlt1), 0.f);
    inter *= fmaxf(fminf(prb2,trb2) - fmaxf(plt2,tlt2), 0.f);
    float evol = fmaxf(fmaxf(prb0,trb0) - fminf(plt0,tlt0), 0.f);
    evol *= fmaxf(fmaxf(prb1,trb1) - fminf(plt1,tlt1), 0.f);
    evol *= fmaxf(fmaxf(prb2,trb2) - fminf(plt2,tlt2), 0.f);
    float uni = pvol + tvol - inter;
    return inter/uni - (evol - uni)/evol;
}

__global__ __launch_bounds__(1024) void fused_kernel(
    const float* __restrict__ pred_kp, const float* __restrict__ pred_boxes,
    const float* __restrict__ tgt_boxes, const float* __restrict__ tgt_kp,
    float* __restrict__ C, float* __restrict__ out_idx)
{
    __shared__ __align__(16) float smem[SMEMF];
    const int bid = blockIdx.x;
    const int tid = threadIdx.x;

    if (bid >= BSZ) {
        // ================= cost-matrix path: 64 preds x 80 tgts per block =================
        const int cb = bid - BSZ;
        const int pb = cb % 75, tb = cb / 75;
        const int p0 = pb * 64, t0 = tb * 80;
        float* s_dk   = smem;            // 80 x 56 (padded, 16B-aligned rows)
        float* s_tbox = smem + 4480;     // 80 x 12: lt0-2, rb0-2, vol, pad, pad, s0-2
        float* s_pk   = smem + 5440;     // 64 x 51

        if (tid < 80) {
            const float* tb6 = tgt_boxes + (size_t)(t0 + tid) * 6;
            float c0=tb6[0], c1=tb6[1], c2=tb6[2], s0=tb6[3], s1=tb6[4], s2=tb6[5];
            float l0=c0-0.5f*s0, l1=c1-0.5f*s1, l2=c2-0.5f*s2;
            float r0=c0+0.5f*s0, r1=c1+0.5f*s1, r2=c2+0.5f*s2;
            float* tw = s_tbox + tid*12;
            tw[0]=l0; tw[1]=l1; tw[2]=l2; tw[3]=r0; tw[4]=r1; tw[5]=r2;
            tw[6]=(r0-l0)*(r1-l1)*(r2-l2);
            tw[9]=s0; tw[10]=s1; tw[11]=s2;
        }
        __syncthreads();
        for (int e = tid; e < 80*K3; e += 1024) {
            int t = e / K3; int c = e - t*K3; int d = c % 3;
            float kp = tgt_kp[(size_t)t0*K3 + e];
            s_dk[t*56 + c] = (kp - s_tbox[t*12 + d]) / s_tbox[t*12 + 9 + d];
        }
        for (int e = tid; e < 64*K3; e += 1024)
            s_pk[e] = pred_kp[(size_t)p0*K3 + e];
        __syncthreads();

        const int pl = tid & 63, g = tid >> 6;
        float a[K3];
        #pragma unroll
        for (int c = 0; c < K3; ++c) a[c] = s_pk[pl*K3 + c];
        const int p = p0 + pl;
        const float* pb6 = pred_boxes + (size_t)p * 6;
        float pc0=pb6[0],pc1=pb6[1],pc2=pb6[2],ps0=pb6[3],ps1=pb6[4],ps2=pb6[5];
        float plt0=pc0-0.5f*ps0, plt1=pc1-0.5f*ps1, plt2=pc2-0.5f*ps2;
        float prb0=pc0+0.5f*ps0, prb1=pc1+0.5f*ps1, prb2=pc2+0.5f*ps2;
        float pvol=(prb0-plt0)*(prb1-plt1)*(prb2-plt2);

        #pragma unroll
        for (int k = 0; k < 5; ++k) {
            int tl = g*5 + k;                       // wave-uniform -> broadcast LDS reads
            const float* bbp = s_dk + tl*56;
            float sum = 0.f;
            #pragma unroll
            for (int c4 = 0; c4 < 12; ++c4) {       // ascending c, serial adds (order fixed)
                float4 q = *(const float4*)(bbp + 4*c4);
                sum += fabsf(a[4*c4+0] - q.x);
                sum += fabsf(a[4*c4+1] - q.y);
                sum += fabsf(a[4*c4+2] - q.z);
                sum += fabsf(a[4*c4+3] - q.w);
            }
            sum += fabsf(a[48] - bbp[48]);
            sum += fabsf(a[49] - bbp[49]);
            sum += fabsf(a[50] - bbp[50]);
            const float* tw = s_tbox + tl*12;
            float g_ = giou_cost(plt0,plt1,plt2,prb0,prb1,prb2,pvol,
                                 tw[0],tw[1],tw[2],tw[3],tw[4],tw[5],tw[6]);
            C[(size_t)p*NTGT + (t0+tl)] = sum - g_;
        }
        return;
    }

    // ================= LAP path: one block per batch =================
    const int b = bid;
    const int ln = tid & 63, w = tid >> 6;
    const int bq0 = b*NQ, bt0 = b*NT;
    float* tile = smem;                 // becomes [50][301] cost tile

    // stage tgt_kp slice into (future) tile area
    for (int e = tid; e < NT*K3; e += 1024)
        tile[e] = tgt_kp[(size_t)bt0*K3 + e];
    __syncthreads();

    // per-lane target row -> registers (every wave redundantly; lanes 0..49)
    float dk[K3];
    float tl0=0,tl1=0,tl2=0,tr0=0,tr1=0,tr2=0,tvol=0;
    if (ln < NT) {
        const float* tb6 = tgt_boxes + (size_t)(bt0+ln)*6;
        float c0=tb6[0],c1=tb6[1],c2=tb6[2],s0=tb6[3],s1=tb6[4],s2=tb6[5];
        tl0=c0-0.5f*s0; tl1=c1-0.5f*s1; tl2=c2-0.5f*s2;
        tr0=c0+0.5f*s0; tr1=c1+0.5f*s1; tr2=c2+0.5f*s2;
        tvol=(tr0-tl0)*(tr1-tl1)*(tr2-tl2);
        #pragma unroll
        for (int c = 0; c < K3; ++c) {
            int d = c % 3;
            float L = (d==0)?tl0:((d==1)?tl1:tl2);
            float S = (d==0)?s0:((d==1)?s1:s2);
            dk[c] = (tile[ln*K3 + c] - L) / S;
        }
    }
    __syncthreads();

    // build cost tile: wave w handles preds p = w, w+16, ... (bitwise same math as C path)
    for (int p = w; p < NQ; p += 16) {
        const float* prow = pred_kp + (size_t)(bq0+p)*K3;
        const float* pb6  = pred_boxes + (size_t)(bq0+p)*6;
        float pc0=pb6[0],pc1=pb6[1],pc2=pb6[2],ps0=pb6[3],ps1=pb6[4],ps2=pb6[5];
        float plt0=pc0-0.5f*ps0, plt1=pc1-0.5f*ps1, plt2=pc2-0.5f*ps2;
        float prb0=pc0+0.5f*ps0, prb1=pc1+0.5f*ps1, prb2=pc2+0.5f*ps2;
        float pvol=(prb0-plt0)*(prb1-plt1)*(prb2-plt2);
        if (ln < NT) {
            float sum = 0.f;
            #pragma unroll
            for (int c = 0; c < K3; ++c) sum += fabsf(prow[c] - dk[c]);
            float g_ = giou_cost(plt0,plt1,plt2,prb0,prb1,prb2,pvol,
                                 tl0,tl1,tl2,tr0,tr1,tr2,tvol);
            tile[ln*TSTRIDE + p] = sum - g_;
        }
    }
    __syncthreads();
    if (w != 0) return;                 // wave 0 continues alone; no more s_barrier

    // ---- register-resident JV shortest-augmenting-path (scipy-exact, float64 duals) ----
    // lane ln owns columns j = ln + 64*s (s=0..4); slot 4 invalid for ln>=44
    double u = 0.0;                     // dual for row ln (ln<50)
    int c4r = -1;                       // col4row[ln]
    double v[5], sh[5];
    int pth[5], r4c[5];
    #pragma unroll
    for (int s = 0; s < 5; ++s) { v[s] = 0.0; r4c[s] = -1; }
    const double DINF = __builtin_inf();

    for (int curRow = 0; curRow < NT; ++curRow) {
        #pragma unroll
        for (int s = 0; s < 5; ++s) { sh[s] = DINF; pth[s] = -1; }
        int SCm = (ln < 44) ? 0 : 0x10;            // invalid slot pre-closed
        unsigned long long SRmask = 0ull;
        int i = curRow;
        double minVal = 0.0;
        int sink = -1;

        while (true) {
            SRmask |= (1ull << i);
            float cf[5];
            #pragma unroll
            for (int s = 0; s < 5; ++s) cf[s] = tile[i*TSTRIDE + ln + 64*s];
            double u_i = __shfl(u, i);
            #pragma unroll
            for (int s = 0; s < 5; ++s) {
                bool open = ((SCm >> s) & 1) == 0;
                double r = ((minVal + (double)cf[s]) - u_i) - v[s];  // reference op order
                bool upd = open && (r < sh[s]);
                sh[s]  = upd ? r : sh[s];
                pth[s] = upd ? i : pth[s];
            }
            // phase 1: exact f64 min over open columns
            double lmin = DINF;
            #pragma unroll
            for (int s = 0; s < 5; ++s) {
                double x = (((SCm >> s) & 1) == 0) ? sh[s] : DINF;
                lmin = fmin(lmin, x);
            }
            double m = wave_min_f64(lmin);
            // phase 2: among value-matching columns, min j; carry row4col in payload
            unsigned lpay = 0xFFFFFFFFu;
            #pragma unroll
            for (int s = 0; s < 5; ++s) {
                bool match = (((SCm >> s) & 1) == 0) && (sh[s] == m);
                unsigned pay = ((unsigned)(ln + 64*s) << 9) | (unsigned)(r4c[s] + 1);
                lpay = (match && pay < lpay) ? pay : lpay;
            }
            unsigned gpay = wave_min_u32(lpay);
            int jstar = (int)(gpay >> 9);
            int rc    = (int)(gpay & 0x1FFu) - 1;
            minVal = m;
            int ow = jstar & 63, sl = jstar >> 6;
            SCm = (ln == ow) ? (SCm | (1 << sl)) : SCm;   // predicated, exec stays full
            if (rc < 0) { sink = jstar; break; }
            i = rc;
        }

        // ---- dual updates (pre-augment col4row) ----
        int cg  = (c4r >= 0) ? c4r : 0;
        int gow = cg & 63, gsl = cg >> 6;
        double g0 = __shfl(sh[0], gow);
        double g1 = __shfl(sh[1], gow);
        double g2 = __shfl(sh[2], gow);
        double g3 = __shfl(sh[3], gow);
        double g4 = __shfl(sh[4], gow);
        double gg = g0;
        gg = (gsl == 1) ? g1 : gg;
        gg = (gsl == 2) ? g2 : gg;
        gg = (gsl == 3) ? g3 : gg;
        gg = (gsl == 4) ? g4 : gg;
        bool inSR = (ln < NT) && ((SRmask >> ln) & 1ull);
        double du = (ln == curRow) ? minVal : (minVal - gg);
        u = inSR ? (u + du) : u;
        #pragma unroll
        for (int s = 0; s < 5; ++s) {
            bool closed = ((SCm >> s) & 1) != 0;
            v[s] = closed ? (v[s] - (minVal - sh[s])) : v[s];
        }

        // ---- augment (all lanes in lockstep; uniform values) ----
        int j = sink;
        while (true) {
            int ow2 = j & 63, sl2 = j >> 6;
            int ps = pth[0];
            ps = (sl2==1) ? pth[1] : ps;
            ps = (sl2==2) ? pth[2] : ps;
            ps = (sl2==3) ? pth[3] : ps;
            ps = (sl2==4) ? pth[4] : ps;
            int ii = __shfl(ps, ow2);               // path[j]
            #pragma unroll
            for (int s = 0; s < 5; ++s)
                r4c[s] = (ln == ow2 && s == sl2) ? ii : r4c[s];   // row4col[j] = ii
            int jj = __shfl(c4r, ii);               // old col4row[ii]
            c4r = (ln == ii) ? j : c4r;             // col4row[ii] = j
            j = jj;
            if (ii == curRow) break;
        }
    }

    // ---- emit indices (argsort of matched pred indices) ----
    int* smem_i = (int*)smem;                       // tile is dead
    __threadfence_block();
    if (ln < NT) smem_i[ln] = c4r;
    __threadfence_block();
    int myc = c4r;
    int rank = 0;
    for (int s2 = 0; s2 < NT; ++s2) rank += (smem_i[s2] < myc) ? 1 : 0;
    if (ln < NT) {
        out_idx[b*(2*NT) + rank]      = (float)myc; // sorted pred (q) indices
        out_idx[b*(2*NT) + NT + rank] = (float)ln;  // matched tgt (t) indices
    }
}

extern "C" void kernel_launch(void* const* d_in, const int* in_sizes, int n_in,
                              void* d_out, int out_size, void* d_ws, size_t ws_size,
                              hipStream_t stream)
{
    const float* pred_kp    = (const float*)d_in[0];
    const float* pred_boxes = (const float*)d_in[1];
    const float* tgt_boxes  = (const float*)d_in[2];
    const float* tgt_kp     = (const float*)d_in[3];
    float* C   = (float*)d_out;
    float* idx = C + NC;
    // blocks 0..15: per-batch LAP (dispatched first); blocks 16..765: cost matrix
    fused_kernel<<<dim3(BSZ + 750), 1024, 0, stream>>>(
        pred_kp, pred_boxes, tgt_boxes, tgt_kp, C, idx);
}

// Round 3
// 150.022 us; speedup vs baseline: 2.2834x; 1.0024x over previous
//
#include <hip/hip_runtime.h>
#include <math.h>

#define BSZ 16
#define NQ 300
#define NT 50
#define K3 51
#define NPRED (BSZ*NQ)     // 4800
#define NTGT  (BSZ*NT)     // 800
#define NC    (NPRED*NTGT) // 3,840,000
#define TSTRIDE 301        // lap tile row stride (floats), odd -> conflict-free
#define SMEMF 15104        // floats: 50*301 tile + slack (60.4 KB)

// ---------------- DPP wave-min helper (wave64, all lanes active) ----------------
template<int CTRL, int RMASK>
__device__ __forceinline__ double dpp_minstep_f64(double x) {
    long long bb = __double_as_longlong(x);
    int lo = (int)(bb & 0xFFFFFFFFll);
    int hi = (int)(bb >> 32);
    int mlo = __builtin_amdgcn_update_dpp(lo, lo, CTRL, RMASK, 0xF, false);
    int mhi = __builtin_amdgcn_update_dpp(hi, hi, CTRL, RMASK, 0xF, false);
    double other = __longlong_as_double(((long long)mhi << 32) | (long long)(unsigned)mlo);
    return fmin(x, other);
}
__device__ __forceinline__ double wave_min_f64(double x) {
    x = dpp_minstep_f64<0xB1, 0xF>(x);
    x = dpp_minstep_f64<0x4E, 0xF>(x);
    x = dpp_minstep_f64<0x141, 0xF>(x);
    x = dpp_minstep_f64<0x140, 0xF>(x);
    x = dpp_minstep_f64<0x142, 0xA>(x);   // lanes 16-31,48-63 <- lane 15/47
    x = dpp_minstep_f64<0x143, 0xC>(x);   // lanes 32-63 <- lane 31; lane 63 = global min
    long long bb = __double_as_longlong(x);
    int lo = __builtin_amdgcn_readlane((int)(bb & 0xFFFFFFFFll), 63);
    int hi = __builtin_amdgcn_readlane((int)(bb >> 32), 63);
    return __longlong_as_double(((long long)hi << 32) | (long long)(unsigned)lo);
}
__device__ __forceinline__ double readlane_f64(double x, int lane) {
    long long bb = __double_as_longlong(x);
    int lo = __builtin_amdgcn_readlane((int)(bb & 0xFFFFFFFFll), lane);
    int hi = __builtin_amdgcn_readlane((int)(bb >> 32), lane);
    return __longlong_as_double(((long long)hi << 32) | (long long)(unsigned)lo);
}

// Identical formula/op-order used by BOTH paths -> bitwise-identical cost values.
__device__ __forceinline__ float giou_cost(
    float plt0, float plt1, float plt2, float prb0, float prb1, float prb2, float pvol,
    float tlt0, float tlt1, float tlt2, float trb0, float trb1, float trb2, float tvol)
{
    float inter = fmaxf(fminf(prb0,trb0) - fmaxf(plt0,tlt0), 0.f);
    inter *= fmaxf(fminf(prb1,trb1) - fmaxf(plt1,tlt1), 0.f);
    inter *= fmaxf(fminf(prb2,trb2) - fmaxf(plt2,tlt2), 0.f);
    float evol = fmaxf(fmaxf(prb0,trb0) - fminf(plt0,tlt0), 0.f);
    evol *= fmaxf(fmaxf(prb1,trb1) - fminf(plt1,tlt1), 0.f);
    evol *= fmaxf(fmaxf(prb2,trb2) - fminf(plt2,tlt2), 0.f);
    float uni = pvol + tvol - inter;
    return inter/uni - (evol - uni)/evol;
}

__global__ __launch_bounds__(1024) void fused_kernel(
    const float* __restrict__ pred_kp, const float* __restrict__ pred_boxes,
    const float* __restrict__ tgt_boxes, const float* __restrict__ tgt_kp,
    float* __restrict__ C, float* __restrict__ out_idx)
{
    __shared__ __align__(16) float smem[SMEMF];
    const int bid = blockIdx.x;
    const int tid = threadIdx.x;

    if (bid >= BSZ) {
        // ================= cost-matrix path: 64 preds x 80 tgts per block =================
        const int cb = bid - BSZ;
        const int pb = cb % 75, tb = cb / 75;
        const int p0 = pb * 64, t0 = tb * 80;
        float* s_dk   = smem;            // 80 x 56 (padded, 16B-aligned rows)
        float* s_tbox = smem + 4480;     // 80 x 12: lt0-2, rb0-2, vol, pad, pad, s0-2
        float* s_pk   = smem + 5440;     // 64 x 51

        if (tid < 80) {
            const float* tb6 = tgt_boxes + (size_t)(t0 + tid) * 6;
            float c0=tb6[0], c1=tb6[1], c2=tb6[2], s0=tb6[3], s1=tb6[4], s2=tb6[5];
            float l0=c0-0.5f*s0, l1=c1-0.5f*s1, l2=c2-0.5f*s2;
            float r0=c0+0.5f*s0, r1=c1+0.5f*s1, r2=c2+0.5f*s2;
            float* tw = s_tbox + tid*12;
            tw[0]=l0; tw[1]=l1; tw[2]=l2; tw[3]=r0; tw[4]=r1; tw[5]=r2;
            tw[6]=(r0-l0)*(r1-l1)*(r2-l2);
            tw[9]=s0; tw[10]=s1; tw[11]=s2;
        }
        __syncthreads();
        for (int e = tid; e < 80*K3; e += 1024) {
            int t = e / K3; int c = e - t*K3; int d = c % 3;
            float kp = tgt_kp[(size_t)t0*K3 + e];
            s_dk[t*56 + c] = (kp - s_tbox[t*12 + d]) / s_tbox[t*12 + 9 + d];
        }
        for (int e = tid; e < 64*K3; e += 1024)
            s_pk[e] = pred_kp[(size_t)p0*K3 + e];
        __syncthreads();

        const int pl = tid & 63, g = tid >> 6;
        float a[K3];
        #pragma unroll
        for (int c = 0; c < K3; ++c) a[c] = s_pk[pl*K3 + c];
        const int p = p0 + pl;
        const float* pb6 = pred_boxes + (size_t)p * 6;
        float pc0=pb6[0],pc1=pb6[1],pc2=pb6[2],ps0=pb6[3],ps1=pb6[4],ps2=pb6[5];
        float plt0=pc0-0.5f*ps0, plt1=pc1-0.5f*ps1, plt2=pc2-0.5f*ps2;
        float prb0=pc0+0.5f*ps0, prb1=pc1+0.5f*ps1, prb2=pc2+0.5f*ps2;
        float pvol=(prb0-plt0)*(prb1-plt1)*(prb2-plt2);

        #pragma unroll
        for (int k = 0; k < 5; ++k) {
            int tl = g*5 + k;                       // wave-uniform -> broadcast LDS reads
            const float* bbp = s_dk + tl*56;
            float sum = 0.f;
            #pragma unroll
            for (int c4 = 0; c4 < 12; ++c4) {       // ascending c, serial adds (order fixed)
                float4 q = *(const float4*)(bbp + 4*c4);
                sum += fabsf(a[4*c4+0] - q.x);
                sum += fabsf(a[4*c4+1] - q.y);
                sum += fabsf(a[4*c4+2] - q.z);
                sum += fabsf(a[4*c4+3] - q.w);
            }
            sum += fabsf(a[48] - bbp[48]);
            sum += fabsf(a[49] - bbp[49]);
            sum += fabsf(a[50] - bbp[50]);
            const float* tw = s_tbox + tl*12;
            float g_ = giou_cost(plt0,plt1,plt2,prb0,prb1,prb2,pvol,
                                 tw[0],tw[1],tw[2],tw[3],tw[4],tw[5],tw[6]);
            C[(size_t)p*NTGT + (t0+tl)] = sum - g_;
        }
        return;
    }

    // ================= LAP path: one block per batch =================
    const int b = bid;
    const int ln = tid & 63, w = tid >> 6;
    const int bq0 = b*NQ, bt0 = b*NT;
    float* tile = smem;                 // becomes [50][301] cost tile

    // stage tgt_kp slice into (future) tile area
    for (int e = tid; e < NT*K3; e += 1024)
        tile[e] = tgt_kp[(size_t)bt0*K3 + e];
    __syncthreads();

    // per-lane target row -> registers (every wave redundantly; lanes 0..49)
    float dk[K3];
    float tl0=0,tl1=0,tl2=0,tr0=0,tr1=0,tr2=0,tvol=0;
    if (ln < NT) {
        const float* tb6 = tgt_boxes + (size_t)(bt0+ln)*6;
        float c0=tb6[0],c1=tb6[1],c2=tb6[2],s0=tb6[3],s1=tb6[4],s2=tb6[5];
        tl0=c0-0.5f*s0; tl1=c1-0.5f*s1; tl2=c2-0.5f*s2;
        tr0=c0+0.5f*s0; tr1=c1+0.5f*s1; tr2=c2+0.5f*s2;
        tvol=(tr0-tl0)*(tr1-tl1)*(tr2-tl2);
        #pragma unroll
        for (int c = 0; c < K3; ++c) {
            int d = c % 3;
            float L = (d==0)?tl0:((d==1)?tl1:tl2);
            float S = (d==0)?s0:((d==1)?s1:s2);
            dk[c] = (tile[ln*K3 + c] - L) / S;
        }
    }
    __syncthreads();

    // build cost tile: wave w handles preds p = w, w+16, ... (bitwise same math as C path)
    for (int p = w; p < NQ; p += 16) {
        const float* prow = pred_kp + (size_t)(bq0+p)*K3;
        const float* pb6  = pred_boxes + (size_t)(bq0+p)*6;
        float pc0=pb6[0],pc1=pb6[1],pc2=pb6[2],ps0=pb6[3],ps1=pb6[4],ps2=pb6[5];
        float plt0=pc0-0.5f*ps0, plt1=pc1-0.5f*ps1, plt2=pc2-0.5f*ps2;
        float prb0=pc0+0.5f*ps0, prb1=pc1+0.5f*ps1, prb2=pc2+0.5f*ps2;
        float pvol=(prb0-plt0)*(prb1-plt1)*(prb2-plt2);
        if (ln < NT) {
            float sum = 0.f;
            #pragma unroll
            for (int c = 0; c < K3; ++c) sum += fabsf(prow[c] - dk[c]);
            float g_ = giou_cost(plt0,plt1,plt2,prb0,prb1,prb2,pvol,
                                 tl0,tl1,tl2,tr0,tr1,tr2,tvol);
            tile[ln*TSTRIDE + p] = sum - g_;
        }
    }
    __syncthreads();
    if (w != 0) return;                 // wave 0 continues alone; no more s_barrier

    // ---- register-resident JV shortest-augmenting-path (scipy-exact, float64 duals) ----
    // lane ln owns columns j = ln + 64*s (s=0..4); slot 4 invalid for ln>=44
    double u = 0.0;                     // dual for row ln (ln<50)
    int c4r = -1;                       // col4row[ln]
    double v[5], sh[5];
    int pth[5];
    #pragma unroll
    for (int s = 0; s < 5; ++s) v[s] = 0.0;
    const double DINF = __builtin_inf();

    for (int curRow = 0; curRow < NT; ++curRow) {
        #pragma unroll
        for (int s = 0; s < 5; ++s) { sh[s] = DINF; pth[s] = -1; }
        int SCm = (ln < 44) ? 0 : 0x10;            // invalid slot pre-closed
        unsigned long long SRmask = 0ull;
        int i = curRow;
        double minVal = 0.0;
        int sink = -1;

        while (true) {
            SRmask |= (1ull << i);
            float cf[5];
            #pragma unroll
            for (int s = 0; s < 5; ++s) cf[s] = tile[i*TSTRIDE + ln + 64*s];
            double u_i = readlane_f64(u, i);       // i is wave-uniform -> v_readlane
            double lmin = DINF;
            #pragma unroll
            for (int s = 0; s < 5; ++s) {
                bool open = ((SCm >> s) & 1) == 0;
                double r = ((minVal + (double)cf[s]) - u_i) - v[s];  // reference op order
                bool upd = open && (r < sh[s]);
                sh[s]  = upd ? r : sh[s];
                pth[s] = upd ? i : pth[s];
                lmin = fmin(lmin, open ? sh[s] : DINF);
            }
            // exact f64 min over open columns
            double m = wave_min_f64(lmin);
            minVal = m;
            // argmin-j: first open column (ascending j = ln+64s) whose sh equals m.
            // j ordering is s-major then lane, so scan s ascending, ctz per ballot.
            unsigned long long b0 = __ballot((((SCm >> 0) & 1) == 0) && (sh[0] == m));
            unsigned long long b1 = __ballot((((SCm >> 1) & 1) == 0) && (sh[1] == m));
            unsigned long long b2 = __ballot((((SCm >> 2) & 1) == 0) && (sh[2] == m));
            unsigned long long b3 = __ballot((((SCm >> 3) & 1) == 0) && (sh[3] == m));
            unsigned long long b4 = __ballot((((SCm >> 4) & 1) == 0) && (sh[4] == m));
            int jstar;
            if      (b0) jstar =       __builtin_ctzll(b0);
            else if (b1) jstar =  64 + __builtin_ctzll(b1);
            else if (b2) jstar = 128 + __builtin_ctzll(b2);
            else if (b3) jstar = 192 + __builtin_ctzll(b3);
            else         jstar = 256 + __builtin_ctzll(b4);
            // close column jstar
            if (ln == (jstar & 63)) SCm |= 1 << (jstar >> 6);
            // row4col[jstar] via col4row ballot (col4row constant during Dijkstra)
            unsigned long long mm = __ballot((ln < NT) && (c4r == jstar));
            if (mm == 0ull) { sink = jstar; break; }
            i = __builtin_ctzll(mm);
        }

        // ---- dual updates (pre-augment col4row) ----
        int cg  = (c4r >= 0) ? c4r : 0;
        int gow = cg & 63, gsl = cg >> 6;
        double g0 = __shfl(sh[0], gow);
        double g1 = __shfl(sh[1], gow);
        double g2 = __shfl(sh[2], gow);
        double g3 = __shfl(sh[3], gow);
        double g4 = __shfl(sh[4], gow);
        double gg = g0;
        gg = (gsl == 1) ? g1 : gg;
        gg = (gsl == 2) ? g2 : gg;
        gg = (gsl == 3) ? g3 : gg;
        gg = (gsl == 4) ? g4 : gg;
        bool inSR = (ln < NT) && ((SRmask >> ln) & 1ull);
        double du = (ln == curRow) ? minVal : (minVal - gg);
        u = inSR ? (u + du) : u;
        #pragma unroll
        for (int s = 0; s < 5; ++s) {
            bool closed = ((SCm >> s) & 1) != 0;
            v[s] = closed ? (v[s] - (minVal - sh[s])) : v[s];
        }

        // ---- augment (uniform j/i chain -> readlane) ----
        int j = sink;
        while (true) {
            int ow2 = j & 63, sl2 = j >> 6;
            int ps = pth[0];
            ps = (sl2==1) ? pth[1] : ps;
            ps = (sl2==2) ? pth[2] : ps;
            ps = (sl2==3) ? pth[3] : ps;
            ps = (sl2==4) ? pth[4] : ps;
            int ii = __builtin_amdgcn_readlane(ps, ow2);   // path[j]
            int jj = __builtin_amdgcn_readlane(c4r, ii);   // old col4row[ii]
            if (ln == ii) c4r = j;                          // col4row[ii] = j
            j = jj;
            if (ii == curRow) break;
        }
    }

    // ---- emit indices (argsort of matched pred indices) ----
    int* smem_i = (int*)smem;                       // tile is dead
    __threadfence_block();
    if (ln < NT) smem_i[ln] = c4r;
    __threadfence_block();
    int myc = c4r;
    int rank = 0;
    for (int s2 = 0; s2 < NT; ++s2) rank += (smem_i[s2] < myc) ? 1 : 0;
    if (ln < NT) {
        out_idx[b*(2*NT) + rank]      = (float)myc; // sorted pred (q) indices
        out_idx[b*(2*NT) + NT + rank] = (float)ln;  // matched tgt (t) indices
    }
}

extern "C" void kernel_launch(void* const* d_in, const int* in_sizes, int n_in,
                              void* d_out, int out_size, void* d_ws, size_t ws_size,
                              hipStream_t stream)
{
    const float* pred_kp    = (const float*)d_in[0];
    const float* pred_boxes = (const float*)d_in[1];
    const float* tgt_boxes  = (const float*)d_in[2];
    const float* tgt_kp     = (const float*)d_in[3];
    float* C   = (float*)d_out;
    float* idx = C + NC;
    // blocks 0..15: per-batch LAP (dispatched first); blocks 16..765: cost matrix
    fused_kernel<<<dim3(BSZ + 750), 1024, 0, stream>>>(
        pred_kp, pred_boxes, tgt_boxes, tgt_kp, C, idx);
}